// Round 1
// baseline (124.022 us; speedup 1.0000x reference)
//
#include <hip/hip_runtime.h>

#define NATOMS 8192
#define DD 128     // embedding dim
#define HH 256     // hidden dim
#define TI 4       // atoms per block in aggregation
#define MAXE 128   // max edges per atom (mean ~20, Poisson; 128 is >>6 sigma)
#define MB 16      // nodes per block in MLP

// out is poisoned 0xAA before every launch; zero it for the atomic reduction.
__global__ void k_zero(float* out) { if (threadIdx.x == 0) out[0] = 0.0f; }

// One block handles TI atoms: O(N) distance sweep, compact valid edges
// (w = exp(-d), row = type[j]*DD) into LDS lists, then sparse-aggregate
// agg[i][:] = sum_e w_e * emb[row_e][:].
__global__ __launch_bounds__(256) void k_agg(const float* __restrict__ pos,
                                             const int* __restrict__ types,
                                             const float* __restrict__ emb,
                                             float* __restrict__ agg) {
  __shared__ float sw[TI][MAXE];
  __shared__ int   srow[TI][MAXE];
  __shared__ int   scnt[TI];
  const int tid = threadIdx.x;
  const int i0 = blockIdx.x * TI;
  if (tid < TI) scnt[tid] = 0;

  float pix[TI], piy[TI], piz[TI];
#pragma unroll
  for (int m = 0; m < TI; ++m) {   // uniform addresses -> scalar loads
    pix[m] = 10.0f * pos[(i0 + m) * 3 + 0];
    piy[m] = 10.0f * pos[(i0 + m) * 3 + 1];
    piz[m] = 10.0f * pos[(i0 + m) * 3 + 2];
  }
  __syncthreads();

  for (int j = tid; j < NATOMS; j += 256) {
    float pjx = 10.0f * pos[j * 3 + 0];
    float pjy = 10.0f * pos[j * 3 + 1];
    float pjz = 10.0f * pos[j * 3 + 2];
#pragma unroll
    for (int m = 0; m < TI; ++m) {
      float dx = pix[m] - pjx, dy = piy[m] - pjy, dz = piz[m] - pjz;
      float d2 = dx * dx;
      d2 = fmaf(dy, dy, d2);
      d2 = fmaf(dz, dz, d2);
      // ref mask: d2 > 1e-12 && sqrt(d2) <= 5  <=>  1e-12 < d2 <= 25 (fp32-exact)
      if (d2 > 1e-12f && d2 <= 25.0f) {
        float w = __expf(-sqrtf(d2));
        int e = atomicAdd(&scnt[m], 1);
        if (e < MAXE) {
          sw[m][e] = w;
          srow[m][e] = types[j] * DD;
        }
      }
    }
  }
  __syncthreads();

  // 256 threads = 2 groups of 128 dims; group g handles atoms {g, g+2}
  const int d = tid & (DD - 1);
  const int g = tid >> 7;
#pragma unroll
  for (int mm = 0; mm < TI; mm += 2) {
    int m = g + mm;
    int nc = min(scnt[m], MAXE);
    float a = 0.0f;
    for (int e = 0; e < nc; ++e)
      a = fmaf(sw[m][e], emb[srow[m][e] + d], a);
    agg[(size_t)(i0 + m) * DD + d] = a;
  }
}

// MLP: e_node = relu([h,agg] @ W1) @ w2, summed into out (kcal/mol).
// Block = 16 nodes. Thread (tx=tid&127, ty=tid>>7) computes hidden units
// {tx, tx+128} for 8 nodes -> 16 FMA per 8 LDS floats (2 b128) per j.
__global__ __launch_bounds__(256) void k_mlp(const int* __restrict__ types,
                                             const float* __restrict__ emb,
                                             const float* __restrict__ agg,
                                             const float* __restrict__ W1,
                                             const float* __restrict__ w2,
                                             float* __restrict__ out) {
  __shared__ float sf[2 * DD][MB];  // feat transposed [j][m], 16 KB
  __shared__ float sred[4];
  const int tid = threadIdx.x;
  const int n0 = blockIdx.x * MB;

  // stage feat = concat(h, agg): conflict-free, consecutive idx -> consecutive LDS
  for (int idx = tid; idx < MB * 2 * DD; idx += 256) {
    int j = idx >> 4;        // 0..255
    int m = idx & (MB - 1);  // 0..15
    float v;
    if (j < DD) v = emb[types[n0 + m] * DD + j];
    else        v = agg[(size_t)(n0 + m) * DD + (j - DD)];
    sf[j][m] = v;
  }
  __syncthreads();

  const int tx = tid & 127;
  const int ty = tid >> 7;
  float acc0[8], acc1[8];
#pragma unroll
  for (int m = 0; m < 8; ++m) { acc0[m] = 0.0f; acc1[m] = 0.0f; }

  const float* fbase = &sf[0][ty * 8];
#pragma unroll 4
  for (int j = 0; j < 2 * DD; ++j) {
    float w0 = W1[j * HH + tx];          // coalesced, L1/L2-hot
    float w1 = W1[j * HH + tx + 128];
    float f[8];
    *(float4*)&f[0] = *(const float4*)(fbase + j * MB);      // LDS broadcast
    *(float4*)&f[4] = *(const float4*)(fbase + j * MB + 4);
#pragma unroll
    for (int m = 0; m < 8; ++m) {
      acc0[m] = fmaf(f[m], w0, acc0[m]);
      acc1[m] = fmaf(f[m], w1, acc1[m]);
    }
  }

  float s0 = 0.0f, s1 = 0.0f;
#pragma unroll
  for (int m = 0; m < 8; ++m) {
    s0 += fmaxf(acc0[m], 0.0f);
    s1 += fmaxf(acc1[m], 0.0f);
  }
  float p = s0 * w2[tx] + s1 * w2[tx + 128];
#pragma unroll
  for (int off = 32; off; off >>= 1) p += __shfl_down(p, off);  // wave64 reduce
  if ((tid & 63) == 0) sred[tid >> 6] = p;
  __syncthreads();
  if (tid == 0)
    atomicAdd(out, (sred[0] + sred[1] + sred[2] + sred[3]) * 0.2390057361376673f);
}

extern "C" void kernel_launch(void* const* d_in, const int* in_sizes, int n_in,
                              void* d_out, int out_size, void* d_ws, size_t ws_size,
                              hipStream_t stream) {
  const float* pos = (const float*)d_in[0];
  const int*   typ = (const int*)d_in[1];
  const float* emb = (const float*)d_in[2];
  const float* W1  = (const float*)d_in[3];
  const float* w2  = (const float*)d_in[4];
  float* out = (float*)d_out;
  float* agg = (float*)d_ws;  // 8192*128 floats = 4 MB scratch

  hipLaunchKernelGGL(k_zero, dim3(1), dim3(64), 0, stream, out);
  hipLaunchKernelGGL(k_agg, dim3(NATOMS / TI), dim3(256), 0, stream,
                     pos, typ, emb, agg);
  hipLaunchKernelGGL(k_mlp, dim3(NATOMS / MB), dim3(256), 0, stream,
                     typ, emb, agg, W1, w2, out);
}